// Round 1
// baseline (1275.283 us; speedup 1.0000x reference)
//
#include <hip/hip_runtime.h>

#define NN 100000
#define EE 3200000
#define FF 128

// ---------------------------------------------------------------- degrees
__global__ __launch_bounds__(256) void k_degrees(const int* __restrict__ ei,
                                                 int* __restrict__ deg_out,
                                                 int* __restrict__ deg_in) {
  int stride = gridDim.x * blockDim.x;
  for (int e = blockIdx.x * blockDim.x + threadIdx.x; e < EE; e += stride) {
    atomicAdd(&deg_out[ei[e]], 1);
    atomicAdd(&deg_in[ei[EE + e]], 1);
  }
}

// ---------------------------------------------------------------- norm scales
__global__ __launch_bounds__(256) void k_scales(const int* __restrict__ deg_out,
                                                const int* __restrict__ deg_in,
                                                float* __restrict__ dout_is,
                                                float* __restrict__ din_is) {
  int i = blockIdx.x * blockDim.x + threadIdx.x;
  if (i < NN) {
    int doo = deg_out[i]; if (doo < 1) doo = 1;
    int dii = deg_in[i];  if (dii < 1) dii = 1;
    dout_is[i] = rsqrtf((float)doo);
    din_is[i]  = rsqrtf((float)dii);
  }
}

// ---------------------------------------------------------------- exclusive scan (single block)
__global__ __launch_bounds__(1024) void k_scan(const int* __restrict__ deg,
                                               int* __restrict__ offs) {
  __shared__ int sums[1024];
  const int T = 1024;
  const int per = (NN + T - 1) / T;   // 98
  int tid = threadIdx.x;
  int start = tid * per;
  int end = start + per; if (end > NN) end = NN;
  if (start > NN) start = NN;
  int s = 0;
  for (int i = start; i < end; ++i) s += deg[i];
  sums[tid] = s;
  __syncthreads();
  for (int off = 1; off < T; off <<= 1) {
    int v = (tid >= off) ? sums[tid - off] : 0;
    __syncthreads();
    sums[tid] += v;
    __syncthreads();
  }
  int run = (tid == 0) ? 0 : sums[tid - 1];
  for (int i = start; i < end; ++i) { offs[i] = run; run += deg[i]; }
  if (tid == T - 1) offs[NN] = run;
}

// ---------------------------------------------------------------- copy int
__global__ __launch_bounds__(256) void k_copy_int(const int* __restrict__ a,
                                                  int* __restrict__ b, int n) {
  int i = blockIdx.x * blockDim.x + threadIdx.x;
  if (i < n) b[i] = a[i];
}

// ---------------------------------------------------------------- CSR scatter
__global__ __launch_bounds__(256) void k_scatter(const int* __restrict__ ei,
                                                 int* __restrict__ cursor,
                                                 int* __restrict__ csr_src) {
  int stride = gridDim.x * blockDim.x;
  for (int e = blockIdx.x * blockDim.x + threadIdx.x; e < EE; e += stride) {
    int d = ei[EE + e];
    int pos = atomicAdd(&cursor[d], 1);
    csr_src[pos] = ei[e];
  }
}

// ---------------------------------------------------------------- pull aggregation
// out[i] = din_is[i] * sum_{e in in(i)} dout_is[src(e)] * x[src(e)]
// one wave (64 lanes) per node, float2 per lane (64*2 = 128 cols)
__global__ __launch_bounds__(256) void k_agg(const float* __restrict__ x,
                                             const float* __restrict__ dout_is,
                                             const float* __restrict__ din_is,
                                             const int* __restrict__ offs,
                                             const int* __restrict__ csr_src,
                                             float* __restrict__ out) {
  int gid = blockIdx.x * blockDim.x + threadIdx.x;
  int node = gid >> 6;
  int lane = threadIdx.x & 63;
  if (node >= NN) return;
  int beg = offs[node], end = offs[node + 1];
  float ax = 0.f, ay = 0.f;
  int e = beg;
  for (; e + 4 <= end; e += 4) {
    int s0 = csr_src[e], s1 = csr_src[e + 1], s2 = csr_src[e + 2], s3 = csr_src[e + 3];
    float c0 = dout_is[s0], c1 = dout_is[s1], c2 = dout_is[s2], c3 = dout_is[s3];
    float2 v0 = *(const float2*)(x + s0 * FF + lane * 2);
    float2 v1 = *(const float2*)(x + s1 * FF + lane * 2);
    float2 v2 = *(const float2*)(x + s2 * FF + lane * 2);
    float2 v3 = *(const float2*)(x + s3 * FF + lane * 2);
    ax = fmaf(c0, v0.x, ax); ay = fmaf(c0, v0.y, ay);
    ax = fmaf(c1, v1.x, ax); ay = fmaf(c1, v1.y, ay);
    ax = fmaf(c2, v2.x, ax); ay = fmaf(c2, v2.y, ay);
    ax = fmaf(c3, v3.x, ax); ay = fmaf(c3, v3.y, ay);
  }
  for (; e < end; ++e) {
    int s = csr_src[e];
    float c = dout_is[s];
    float2 v = *(const float2*)(x + s * FF + lane * 2);
    ax = fmaf(c, v.x, ax); ay = fmaf(c, v.y, ay);
  }
  float di = din_is[node];
  float2 r; r.x = ax * di; r.y = ay * di;
  *(float2*)(out + node * FF + lane * 2) = r;
}

// ---------------------------------------------------------------- GEMM + bias + PReLU
// out[i][j] = prelu(sum_k X[i][k] * W[k][j] + b[j])
// block: 256 threads, 64 rows. W staged in k-tiles of 32 rows (16KB LDS).
__global__ __launch_bounds__(256) void k_gemm(const float* __restrict__ X,
                                              const float* __restrict__ W,
                                              const float* __restrict__ bias,
                                              const float* __restrict__ pa,
                                              float* __restrict__ out) {
  __shared__ float Xs[64][FF + 1];   // padded: bank-conflict-free scalar reads
  __shared__ float Wt[32][FF];
  int tid = threadIdx.x;
  int row0 = blockIdx.x * 64;

  // stage 64 X rows
  for (int t = tid; t < 64 * (FF / 4); t += 256) {
    int r = t >> 5;              // 32 float4 per row
    int c4 = (t & 31) * 4;
    int row = row0 + r;
    float4 v = make_float4(0.f, 0.f, 0.f, 0.f);
    if (row < NN) v = *(const float4*)(X + row * FF + c4);
    Xs[r][c4 + 0] = v.x; Xs[r][c4 + 1] = v.y; Xs[r][c4 + 2] = v.z; Xs[r][c4 + 3] = v.w;
  }

  int rp = tid >> 3;             // 0..31 -> row pair
  int ia = rp * 2, ib = ia + 1;
  int j0 = (tid & 7) * 4;        // 0..28, covers 4 regions of 32 cols

  float4 acc0q0 = make_float4(0,0,0,0), acc0q1 = acc0q0, acc0q2 = acc0q0, acc0q3 = acc0q0;
  float4 acc1q0 = acc0q0, acc1q1 = acc0q0, acc1q2 = acc0q0, acc1q3 = acc0q0;

  for (int kt = 0; kt < 4; ++kt) {
    __syncthreads();
    {
      const float4* W4 = (const float4*)(W + kt * 32 * FF);
      float4* Wt4 = (float4*)(&Wt[0][0]);
      for (int t = tid; t < 32 * FF / 4; t += 256) Wt4[t] = W4[t];
    }
    __syncthreads();
#pragma unroll
    for (int k = 0; k < 32; ++k) {
      float xa = Xs[ia][kt * 32 + k];
      float xb = Xs[ib][kt * 32 + k];
      float4 w0 = *(const float4*)(&Wt[k][j0 + 0]);
      float4 w1 = *(const float4*)(&Wt[k][j0 + 32]);
      float4 w2 = *(const float4*)(&Wt[k][j0 + 64]);
      float4 w3 = *(const float4*)(&Wt[k][j0 + 96]);
      acc0q0.x = fmaf(xa, w0.x, acc0q0.x); acc0q0.y = fmaf(xa, w0.y, acc0q0.y);
      acc0q0.z = fmaf(xa, w0.z, acc0q0.z); acc0q0.w = fmaf(xa, w0.w, acc0q0.w);
      acc0q1.x = fmaf(xa, w1.x, acc0q1.x); acc0q1.y = fmaf(xa, w1.y, acc0q1.y);
      acc0q1.z = fmaf(xa, w1.z, acc0q1.z); acc0q1.w = fmaf(xa, w1.w, acc0q1.w);
      acc0q2.x = fmaf(xa, w2.x, acc0q2.x); acc0q2.y = fmaf(xa, w2.y, acc0q2.y);
      acc0q2.z = fmaf(xa, w2.z, acc0q2.z); acc0q2.w = fmaf(xa, w2.w, acc0q2.w);
      acc0q3.x = fmaf(xa, w3.x, acc0q3.x); acc0q3.y = fmaf(xa, w3.y, acc0q3.y);
      acc0q3.z = fmaf(xa, w3.z, acc0q3.z); acc0q3.w = fmaf(xa, w3.w, acc0q3.w);
      acc1q0.x = fmaf(xb, w0.x, acc1q0.x); acc1q0.y = fmaf(xb, w0.y, acc1q0.y);
      acc1q0.z = fmaf(xb, w0.z, acc1q0.z); acc1q0.w = fmaf(xb, w0.w, acc1q0.w);
      acc1q1.x = fmaf(xb, w1.x, acc1q1.x); acc1q1.y = fmaf(xb, w1.y, acc1q1.y);
      acc1q1.z = fmaf(xb, w1.z, acc1q1.z); acc1q1.w = fmaf(xb, w1.w, acc1q1.w);
      acc1q2.x = fmaf(xb, w2.x, acc1q2.x); acc1q2.y = fmaf(xb, w2.y, acc1q2.y);
      acc1q2.z = fmaf(xb, w2.z, acc1q2.z); acc1q2.w = fmaf(xb, w2.w, acc1q2.w);
      acc1q3.x = fmaf(xb, w3.x, acc1q3.x); acc1q3.y = fmaf(xb, w3.y, acc1q3.y);
      acc1q3.z = fmaf(xb, w3.z, acc1q3.z); acc1q3.w = fmaf(xb, w3.w, acc1q3.w);
    }
  }

  // epilogue: bias + PReLU + store
#pragma unroll
  for (int q = 0; q < 4; ++q) {
    int col = j0 + 32 * q;
    float4 b4 = *(const float4*)(bias + col);
    float4 a4 = *(const float4*)(pa + col);
    float4 aq0 = (q == 0) ? acc0q0 : (q == 1) ? acc0q1 : (q == 2) ? acc0q2 : acc0q3;
    float4 aq1 = (q == 0) ? acc1q0 : (q == 1) ? acc1q1 : (q == 2) ? acc1q2 : acc1q3;
    int ra = row0 + ia, rb = row0 + ib;
    if (ra < NN) {
      float4 v;
      v.x = aq0.x + b4.x; v.y = aq0.y + b4.y; v.z = aq0.z + b4.z; v.w = aq0.w + b4.w;
      v.x = v.x >= 0.f ? v.x : a4.x * v.x;
      v.y = v.y >= 0.f ? v.y : a4.y * v.y;
      v.z = v.z >= 0.f ? v.z : a4.z * v.z;
      v.w = v.w >= 0.f ? v.w : a4.w * v.w;
      *(float4*)(out + ra * FF + col) = v;
    }
    if (rb < NN) {
      float4 v;
      v.x = aq1.x + b4.x; v.y = aq1.y + b4.y; v.z = aq1.z + b4.z; v.w = aq1.w + b4.w;
      v.x = v.x >= 0.f ? v.x : a4.x * v.x;
      v.y = v.y >= 0.f ? v.y : a4.y * v.y;
      v.z = v.z >= 0.f ? v.z : a4.z * v.z;
      v.w = v.w >= 0.f ? v.w : a4.w * v.w;
      *(float4*)(out + rb * FF + col) = v;
    }
  }
}

// ---------------------------------------------------------------- launch
extern "C" void kernel_launch(void* const* d_in, const int* in_sizes, int n_in,
                              void* d_out, int out_size, void* d_ws, size_t ws_size,
                              hipStream_t stream) {
  const float* features = (const float*)d_in[0];
  const int*   ei       = (const int*)d_in[1];   // [2][E], int32 (JAX x64 disabled)
  const float* W1       = (const float*)d_in[2];
  const float* b1       = (const float*)d_in[3];
  const float* W2       = (const float*)d_in[4];
  const float* b2       = (const float*)d_in[5];
  const float* pa       = (const float*)d_in[6];
  float* out = (float*)d_out;

  char* ws = (char*)d_ws;
  size_t off = 0;
  auto alloc = [&](size_t bytes) -> void* {
    void* p = ws + off;
    off += (bytes + 255) & ~(size_t)255;
    return p;
  };
  int*   deg     = (int*)alloc((size_t)2 * NN * 4);  // deg_out | deg_in (contiguous for one memset)
  int*   deg_out = deg;
  int*   deg_in  = deg + NN;
  float* dout_is = (float*)alloc((size_t)NN * 4);
  float* din_is  = (float*)alloc((size_t)NN * 4);
  int*   offs    = (int*)alloc((size_t)(NN + 1) * 4);
  int*   cursor  = (int*)alloc((size_t)NN * 4);
  int*   csr_src = (int*)alloc((size_t)EE * 4);
  float* tmp     = (float*)alloc((size_t)NN * FF * 4);

  hipMemsetAsync(deg, 0, (size_t)2 * NN * 4, stream);

  k_degrees<<<1024, 256, 0, stream>>>(ei, deg_out, deg_in);
  k_scales<<<(NN + 255) / 256, 256, 0, stream>>>(deg_out, deg_in, dout_is, din_is);
  k_scan<<<1, 1024, 0, stream>>>(deg_in, offs);
  k_copy_int<<<(NN + 255) / 256, 256, 0, stream>>>(offs, cursor, NN);
  k_scatter<<<1024, 256, 0, stream>>>(ei, cursor, csr_src);

  // layer 1: agg(features) -> tmp ; gemm(tmp, W1) -> out (holds h1)
  k_agg<<<NN / 4, 256, 0, stream>>>(features, dout_is, din_is, offs, csr_src, tmp);
  k_gemm<<<(NN + 63) / 64, 256, 0, stream>>>(tmp, W1, b1, pa, out);

  // layer 2: agg(h1=out) -> tmp ; gemm(tmp, W2) -> out
  k_agg<<<NN / 4, 256, 0, stream>>>(out, dout_is, din_is, offs, csr_src, tmp);
  k_gemm<<<(NN + 63) / 64, 256, 0, stream>>>(tmp, W2, b2, pa, out);
}